// Round 3
// baseline (4234.339 us; speedup 1.0000x reference)
//
#include <hip/hip_runtime.h>
#include <math.h>

#define LRELU 0.1f
#define SQRT_HALF 0.7071067811865476f

constexpr int T_LEN = 16384;

typedef __attribute__((ext_vector_type(8))) short short8;
typedef __attribute__((ext_vector_type(4))) float f32x4;

__device__ __host__ inline void bsplit(float v, unsigned short& hi, unsigned short& lo) {
    unsigned u = __float_as_uint(v);
    unsigned rh = (u + 0x7FFFu + ((u >> 16) & 1u)) >> 16;
    float fh = __uint_as_float(rh << 16);
    float r = v - fh;
    unsigned u2 = __float_as_uint(r);
    unsigned rl = (u2 + 0x7FFFu + ((u2 >> 16) & 1u)) >> 16;
    hi = (unsigned short)rh; lo = (unsigned short)rl;
}
__device__ inline float b2f(unsigned short s) { return __uint_as_float(((unsigned)s) << 16); }

// ======================= prep =======================
// Apk[li][ks 12][m16 16][h 2][lane 64][j 8]   (conv weights bf16 hi/lo)
// Spk[li][ks2 4][m8 8][h 2][lane 64][j 8]
// pre_wT[li][s][i][o] ; wup{1,2}T[(i*128+o)*4+r] = up_w[o][i][3-r] ; o{1,2}T[i][o]
__global__ void prep_w2(const float* __restrict__ wn_ws, const float* __restrict__ sk_ws,
                        const float* __restrict__ pre_ws,
                        const float* __restrict__ up1_w, const float* __restrict__ up2_w,
                        const float* __restrict__ o1w, const float* __restrict__ o2w,
                        unsigned short* __restrict__ Apk, unsigned short* __restrict__ Spk,
                        float* __restrict__ pre_wT, float* __restrict__ wup1T,
                        float* __restrict__ wup2T, float* __restrict__ o1T, float* __restrict__ o2T)
{
    int b = blockIdx.x, tid = threadIdx.x;
    if (b < 360) {                      // Apk: (li, ks)
        __shared__ float sl[256][32];
        int li = b / 12, ks = b % 12;
        int tap = ks >> 2, i0 = (ks & 3) * 32;
        for (int j = tid; j < 8192; j += 256) {
            int o = j >> 5, ii = j & 31;
            sl[o][ii] = wn_ws[((size_t)(li * 256 + o) * 128 + i0 + ii) * 3 + tap];
        }
        __syncthreads();
        size_t obase = ((size_t)(li * 12 + ks)) * 16384;  // 16 m16 * 2 h * 512
        for (int e = tid; e < 8192; e += 256) {
            int j = e & 7, l = (e >> 3) & 63, m16 = e >> 9;
            int o = m16 * 16 + (l & 15);
            int ii = 4 * (l >> 4) + (j & 3) + 16 * (j >> 2);
            unsigned short hi, lo; bsplit(sl[o][ii], hi, lo);
            Apk[obase + (size_t)m16 * 1024 + 0 * 512 + l * 8 + j] = hi;
            Apk[obase + (size_t)m16 * 1024 + 1 * 512 + l * 8 + j] = lo;
        }
    } else if (b < 480) {               // Spk: (li, ks2)
        __shared__ float s2[128][32];
        int bb = b - 360;
        int li = bb / 4, ks2 = bb % 4;
        int i0 = ks2 * 32;
        for (int j = tid; j < 4096; j += 256) {
            int o = j >> 5, ii = j & 31;
            s2[o][ii] = sk_ws[(size_t)(li * 128 + o) * 128 + i0 + ii];
        }
        __syncthreads();
        size_t obase = ((size_t)(li * 4 + ks2)) * 8192;   // 8 m8 * 2 h * 512
        for (int e = tid; e < 4096; e += 256) {
            int j = e & 7, l = (e >> 3) & 63, m8 = e >> 9;
            int o = m8 * 16 + (l & 15);
            int ii = 4 * (l >> 4) + (j & 3) + 16 * (j >> 2);
            unsigned short hi, lo; bsplit(s2[o][ii], hi, lo);
            Spk[obase + (size_t)m8 * 1024 + 0 * 512 + l * 8 + j] = hi;
            Spk[obase + (size_t)m8 * 1024 + 1 * 512 + l * 8 + j] = lo;
        }
    } else {                            // misc elementwise
        int e = (b - 480) * 256 + tid;
        if (e < 245760) {               // pre_wT[li][s][i][o]
            int o = e & 127, i = (e >> 7) & 127, s = (e / 16384) % 3, li = e / 49152;
            pre_wT[e] = pre_ws[(((size_t)li * 128 + o) * 128 + i) * 3 + s];
        } else if (e < 245760 + 16384) {
            int e2 = e - 245760; int i = e2 >> 7, o = e2 & 127;
            float4 f = *(const float4*)(up1_w + ((size_t)o * 128 + i) * 4);
            float4 g = {f.w, f.z, f.y, f.x};
            *(float4*)(wup1T + (size_t)e2 * 4) = g;
        } else if (e < 245760 + 32768) {
            int e2 = e - 245760 - 16384; int i = e2 >> 7, o = e2 & 127;
            float4 f = *(const float4*)(up2_w + ((size_t)o * 128 + i) * 4);
            float4 g = {f.w, f.z, f.y, f.x};
            *(float4*)(wup2T + (size_t)e2 * 4) = g;
        } else if (e < 245760 + 32768 + 16384) {
            int e2 = e - 245760 - 32768; int o = e2 & 127, i = e2 >> 7;
            o1T[e2] = o1w[o * 128 + i];
        } else if (e < 245760 + 32768 + 32768) {
            int e2 = e - 245760 - 32768 - 16384; int o = e2 & 127, i = e2 >> 7;
            o2T[e2] = o2w[o * 128 + i];
        }
    }
}

// ======================= fused front-end =======================
// grid 4 (n), 512 threads; whole L=64 pipeline in LDS
__global__ __launch_bounds__(512, 1)
void fe_front(const float* __restrict__ mel, const float* __restrict__ in_w,
              const float* __restrict__ in_b, const float* __restrict__ pre_wT,
              const float* __restrict__ pre_b, float* __restrict__ xf64)
{
    __shared__ float mels[80][64];
    __shared__ float xa[128][64];
    __shared__ float xb[128][64];
    const int n = blockIdx.x, tid = threadIdx.x;
    const int t = tid & 63;
    const int ob = __builtin_amdgcn_readfirstlane((tid >> 6) * 16);

    for (int j = tid; j < 80 * 64; j += 512) mels[j >> 6][j & 63] = mel[(size_t)n * 80 * 64 + j];
    __syncthreads();

    float acc[16];
    #pragma unroll
    for (int oo = 0; oo < 16; oo++) acc[oo] = in_b[ob + oo];
    for (int i = 0; i < 80; i++) {
        float xv = mels[i][t];
        #pragma unroll
        for (int oo = 0; oo < 16; oo++) acc[oo] = fmaf(in_w[(ob + oo) * 80 + i], xv, acc[oo]);
    }
    #pragma unroll
    for (int oo = 0; oo < 16; oo++) xa[ob + oo][t] = acc[oo];
    __syncthreads();

    float* cur = &xa[0][0];
    float* nxt = &xb[0][0];
    for (int li = 0; li < 5; li++) {
        int d = 1 << li;
        float a2[16];
        #pragma unroll
        for (int oo = 0; oo < 16; oo++) a2[oo] = pre_b[li * 128 + ob + oo];
        for (int i = 0; i < 128; i++) {
            float x0 = cur[i * 64 + t];
            int tm = t - d, tp = t + d;
            float xm = 0.f, xp = 0.f;
            if (tm >= 0) xm = cur[i * 64 + tm];
            if (tp < 64) xp = cur[i * 64 + tp];
            const float* wp = pre_wT + ((size_t)(li * 3) * 128 + i) * 128 + ob;
            #pragma unroll
            for (int oo = 0; oo < 16; oo++) {
                a2[oo] = fmaf(wp[oo], xm, a2[oo]);
                a2[oo] = fmaf(wp[16384 + oo], x0, a2[oo]);
                a2[oo] = fmaf(wp[32768 + oo], xp, a2[oo]);
            }
        }
        #pragma unroll
        for (int oo = 0; oo < 16; oo++) {
            float y = a2[oo];
            y = y > 0.f ? y : LRELU * y;
            nxt[(ob + oo) * 64 + t] = (y + cur[(ob + oo) * 64 + t]) * SQRT_HALF;
        }
        __syncthreads();
        float* tmp = cur; cur = nxt; nxt = tmp;
    }
    #pragma unroll
    for (int oo = 0; oo < 16; oo++)
        xf64[(size_t)(n * 128 + ob + oo) * 64 + t] = cur[(ob + oo) * 64 + t];
}

// ======================= transpose-conv upsample =======================
// q on lanes; waves own 16-o chunks; weights via wave-uniform loads
__global__ __launch_bounds__(512, 2)
void fe_up2(const float* __restrict__ in, float* __restrict__ out,
            const float* __restrict__ wupT, const float* __restrict__ bias, int Lin)
{
    __shared__ float xs[128][64];
    const int n = blockIdx.y, qb = blockIdx.x * 64;
    const int tid = threadIdx.x;
    const int q = tid & 63;
    const int ob = __builtin_amdgcn_readfirstlane((tid >> 6) * 16);
    const int Lout = 4 * Lin;

    for (int j = tid; j < 128 * 64; j += 512) {
        int i = j >> 6, qq = j & 63;
        xs[i][qq] = in[(size_t)(n * 128 + i) * Lin + qb + qq];
    }
    __syncthreads();

    float acc[16][4];
    #pragma unroll
    for (int oo = 0; oo < 16; oo++)
        #pragma unroll
        for (int r = 0; r < 4; r++) acc[oo][r] = 0.f;

    for (int i = 0; i < 128; i++) {
        float xv = xs[i][q];
        const float4* wp = (const float4*)wupT + i * 128 + ob;
        #pragma unroll
        for (int oo = 0; oo < 16; oo++) {
            float4 w4 = wp[oo];
            acc[oo][0] = fmaf(w4.x, xv, acc[oo][0]);
            acc[oo][1] = fmaf(w4.y, xv, acc[oo][1]);
            acc[oo][2] = fmaf(w4.z, xv, acc[oo][2]);
            acc[oo][3] = fmaf(w4.w, xv, acc[oo][3]);
        }
    }
    #pragma unroll
    for (int oo = 0; oo < 16; oo++) {
        int o = ob + oo;
        float bo = bias[o];
        float4 v;
        float a0 = acc[oo][0] + bo, a1 = acc[oo][1] + bo, a2 = acc[oo][2] + bo, a3 = acc[oo][3] + bo;
        v.x = a0 > 0.f ? a0 : LRELU * a0;
        v.y = a1 > 0.f ? a1 : LRELU * a1;
        v.z = a2 > 0.f ? a2 : LRELU * a2;
        v.w = a3 > 0.f ? a3 : LRELU * a3;
        *(float4*)(out + (size_t)(n * 128 + o) * Lout + (size_t)(qb + q) * 4) = v;
    }
}

// 16x repeat into transposed bf16 hi/lo planes [n][t][128]
__global__ void fe_repeat2(const float* __restrict__ x1024,
                           unsigned short* __restrict__ XTh, unsigned short* __restrict__ XTl)
{
    size_t idx = (size_t)blockIdx.x * 256 + threadIdx.x;   // 8,388,608
    int ch = (int)(idx & 127);
    int t = (int)((idx >> 7) & 16383);
    int n = (int)(idx >> 21);
    float v = x1024[((size_t)(n * 128 + ch)) * 1024 + (t >> 4)];
    unsigned short hi, lo; bsplit(v, hi, lo);
    XTh[idx] = hi; XTl[idx] = lo;
}

__global__ void zero_sk(float4* __restrict__ SK)
{
    size_t idx = (size_t)blockIdx.x * 256 + threadIdx.x;   // 2,097,152 float4
    float4 z = {0.f, 0.f, 0.f, 0.f};
    SK[idx] = z;
}

// ======================= WaveNet layer (MFMA, global-B) =======================
__global__ __launch_bounds__(256, 2)
void wn_layer(const unsigned short* __restrict__ Xh, const unsigned short* __restrict__ Xl,
              unsigned short* __restrict__ Yh, unsigned short* __restrict__ Yl,
              float* __restrict__ Skips,
              const unsigned short* __restrict__ Apk,  // [12][16][2][64][8]
              const float* __restrict__ gb,
              const unsigned short* __restrict__ Spk,  // [4][8][2][64][8]
              const float* __restrict__ skb,
              int dil)
{
    __shared__ short Gbuf[4 * 2 * 8 * 64 * 8];   // 64 KB

    const int n = blockIdx.y;
    const int t0 = blockIdx.x * 128;
    const int tid = threadIdx.x;
    const int lane = tid & 63;
    const int w = tid >> 6;

    const size_t nOff = (size_t)n * T_LEN * 128;
    const unsigned short* XhN = Xh + nOff;
    const unsigned short* XlN = Xl + nOff;

    f32x4 acc[4][8];
    const f32x4 z4 = {0.f, 0.f, 0.f, 0.f};
    #pragma unroll
    for (int mf = 0; mf < 4; mf++)
        #pragma unroll
        for (int nf = 0; nf < 8; nf++) acc[mf][nf] = z4;

    const int m16c[4] = {2 * w, 2 * w + 1, 8 + 2 * w, 9 + 2 * w};
    const short8* ap = (const short8*)Apk;
    const int cb = 4 * (lane >> 4);
    const int tl = lane & 15;

    for (int ks = 0; ks < 12; ks++) {
        const int s = ks >> 2;
        const int i0 = (ks & 3) * 32;
        const int tsh = t0 + (s - 1) * dil;
        short8 Ah[4], Al[4];
        #pragma unroll
        for (int mf = 0; mf < 4; mf++) {
            int ib = (ks * 16 + m16c[mf]) * 2 * 64 + lane;
            Ah[mf] = ap[ib];
            Al[mf] = ap[ib + 64];
        }
        #pragma unroll
        for (int nf = 0; nf < 8; nf++) {
            int t = tsh + nf * 16 + tl;
            union { short8 s8; uint2 u[2]; } Bh, Bl;
            Bh.u[0] = Bh.u[1] = Bl.u[0] = Bl.u[1] = make_uint2(0u, 0u);
            if ((unsigned)t < (unsigned)T_LEN) {
                size_t a0 = (size_t)t * 128 + i0 + cb;
                Bh.u[0] = *(const uint2*)(XhN + a0);
                Bh.u[1] = *(const uint2*)(XhN + a0 + 16);
                Bl.u[0] = *(const uint2*)(XlN + a0);
                Bl.u[1] = *(const uint2*)(XlN + a0 + 16);
            }
            #pragma unroll
            for (int mf = 0; mf < 4; mf++) {
                acc[mf][nf] = __builtin_amdgcn_mfma_f32_16x16x32_bf16(Ah[mf], Bh.s8, acc[mf][nf], 0, 0, 0);
                acc[mf][nf] = __builtin_amdgcn_mfma_f32_16x16x32_bf16(Al[mf], Bh.s8, acc[mf][nf], 0, 0, 0);
                acc[mf][nf] = __builtin_amdgcn_mfma_f32_16x16x32_bf16(Ah[mf], Bl.s8, acc[mf][nf], 0, 0, 0);
            }
        }
    }

    // gating -> Gbuf (already in skip-B fragment layout: j = r + 4*mf2, k-chunk = w)
    float bt[2][4], bs[2][4];
    #pragma unroll
    for (int mf2 = 0; mf2 < 2; mf2++)
        #pragma unroll
        for (int r = 0; r < 4; r++) {
            int ch = (2 * w + mf2) * 16 + cb + r;
            bt[mf2][r] = gb[ch];
            bs[mf2][r] = gb[128 + ch];
        }
    #pragma unroll
    for (int nf = 0; nf < 8; nf++) {
        short8 hv, lv;
        #pragma unroll
        for (int mf2 = 0; mf2 < 2; mf2++)
            #pragma unroll
            for (int r = 0; r < 4; r++) {
                float g1 = acc[mf2][nf][r] + bt[mf2][r];
                float g2 = acc[mf2 + 2][nf][r] + bs[mf2][r];
                float gv = tanhf(g1) * (1.f / (1.f + expf(-g2)));
                unsigned short hi, lo; bsplit(gv, hi, lo);
                hv[4 * mf2 + r] = (short)hi;
                lv[4 * mf2 + r] = (short)lo;
            }
        *(short8*)&Gbuf[((w * 2 + 0) * 8 + nf) * 512 + lane * 8] = hv;
        *(short8*)&Gbuf[((w * 2 + 1) * 8 + nf) * 512 + lane * 8] = lv;
    }
    __syncthreads();

    // skip GEMM
    f32x4 acc2[2][8];
    #pragma unroll
    for (int mf2 = 0; mf2 < 2; mf2++)
        #pragma unroll
        for (int nf = 0; nf < 8; nf++) acc2[mf2][nf] = z4;

    const short8* sp = (const short8*)Spk;
    #pragma unroll
    for (int ks2 = 0; ks2 < 4; ks2++) {
        short8 A2h[2], A2l[2];
        #pragma unroll
        for (int mf2 = 0; mf2 < 2; mf2++) {
            int ib = (ks2 * 8 + 2 * w + mf2) * 2 * 64 + lane;
            A2h[mf2] = sp[ib];
            A2l[mf2] = sp[ib + 64];
        }
        #pragma unroll
        for (int nf = 0; nf < 8; nf++) {
            short8 Bh = *(const short8*)&Gbuf[((ks2 * 2 + 0) * 8 + nf) * 512 + lane * 8];
            short8 Bl = *(const short8*)&Gbuf[((ks2 * 2 + 1) * 8 + nf) * 512 + lane * 8];
            #pragma unroll
            for (int mf2 = 0; mf2 < 2; mf2++) {
                acc2[mf2][nf] = __builtin_amdgcn_mfma_f32_16x16x32_bf16(A2h[mf2], Bh, acc2[mf2][nf], 0, 0, 0);
                acc2[mf2][nf] = __builtin_amdgcn_mfma_f32_16x16x32_bf16(A2l[mf2], Bh, acc2[mf2][nf], 0, 0, 0);
                acc2[mf2][nf] = __builtin_amdgcn_mfma_f32_16x16x32_bf16(A2h[mf2], Bl, acc2[mf2][nf], 0, 0, 0);
            }
        }
    }

    // epilogue
    unsigned short* YhN = Yh + nOff;
    unsigned short* YlN = Yl + nOff;
    float* Sk = Skips + (size_t)n * 128 * T_LEN;
    #pragma unroll
    for (int mf2 = 0; mf2 < 2; mf2++) {
        const int cb2 = (2 * w + mf2) * 16 + cb;
        float bo[4];
        #pragma unroll
        for (int r = 0; r < 4; r++) bo[r] = skb[cb2 + r];
        #pragma unroll
        for (int nf = 0; nf < 8; nf++) {
            int t = t0 + nf * 16 + tl;
            size_t a0 = (size_t)t * 128 + cb2;
            union { uint2 u; unsigned short s[4]; } rh, rl, wh, wl;
            rh.u = *(const uint2*)(XhN + a0);
            rl.u = *(const uint2*)(XlN + a0);
            #pragma unroll
            for (int r = 0; r < 4; r++) {
                float xin = b2f(rh.s[r]) + b2f(rl.s[r]);
                float sv = acc2[mf2][nf][r] + bo[r];
                float xo = sv + xin;
                unsigned short hi, lo; bsplit(xo, hi, lo);
                wh.s[r] = hi; wl.s[r] = lo;
                size_t ska = (size_t)(cb2 + r) * T_LEN + t;
                Sk[ska] = Sk[ska] + sv;
            }
            *(uint2*)(YhN + a0) = wh.u;
            *(uint2*)(YlN + a0) = wl.u;
        }
    }
}

// ======================= output stack =======================
template<bool RELU_IN>
__global__ __launch_bounds__(256, 2)
void os_conv(const float* __restrict__ In0, float* __restrict__ Out,
             const float* __restrict__ wTr, const float* __restrict__ bias)
{
    __shared__ float xt[128][64];
    __shared__ float wsk[16][128];
    const int n = blockIdx.y, t0 = blockIdx.x * 64;
    const int tid = threadIdx.x, tg = tid & 7, pg = tid >> 3;
    const float* In = In0 + (size_t)n * 128 * T_LEN;

    for (int j = tid * 4; j < 128 * 64; j += 256 * 4) {
        int i = j >> 6, tt = j & 63;
        float4 v = *reinterpret_cast<const float4*>(In + (size_t)i * T_LEN + t0 + tt);
        if (RELU_IN) {
            v.x = fmaxf(v.x, 0.f); v.y = fmaxf(v.y, 0.f);
            v.z = fmaxf(v.z, 0.f); v.w = fmaxf(v.w, 0.f);
        }
        *reinterpret_cast<float4*>(&xt[i][tt]) = v;
    }
    float acc[4][8];
    #pragma unroll
    for (int a = 0; a < 4; a++)
        #pragma unroll
        for (int b = 0; b < 8; b++) acc[a][b] = 0.f;
    __syncthreads();

    for (int ic = 0; ic < 128; ic += 16) {
        for (int j = tid * 4; j < 16 * 128; j += 256 * 4) {
            int kk = j >> 7; int o = j & 127;
            *reinterpret_cast<float4*>(&wsk[kk][o]) =
                *reinterpret_cast<const float4*>(wTr + ((ic + kk) << 7) + o);
        }
        __syncthreads();
        #pragma unroll
        for (int kk = 0; kk < 16; kk++) {
            float4 wv = *reinterpret_cast<const float4*>(&wsk[kk][pg * 4]);
            float4 ga = *reinterpret_cast<const float4*>(&xt[ic + kk][tg * 8]);
            float4 gbv = *reinterpret_cast<const float4*>(&xt[ic + kk][tg * 8 + 4]);
            float xv[8] = {ga.x, ga.y, ga.z, ga.w, gbv.x, gbv.y, gbv.z, gbv.w};
            float wl[4] = {wv.x, wv.y, wv.z, wv.w};
            #pragma unroll
            for (int a = 0; a < 4; a++)
                #pragma unroll
                for (int b = 0; b < 8; b++)
                    acc[a][b] = fmaf(wl[a], xv[b], acc[a][b]);
        }
        __syncthreads();
    }

    float* Op = Out + (size_t)n * 128 * T_LEN;
    #pragma unroll
    for (int a = 0; a < 4; a++) {
        int o = pg * 4 + a;
        float bo = bias[o];
        size_t base = (size_t)o * T_LEN + t0 + tg * 8;
        #pragma unroll
        for (int h = 0; h < 2; h++) {
            float4 v;
            v.x = fmaxf(acc[a][h * 4 + 0] + bo, 0.f);
            v.y = fmaxf(acc[a][h * 4 + 1] + bo, 0.f);
            v.z = fmaxf(acc[a][h * 4 + 2] + bo, 0.f);
            v.w = fmaxf(acc[a][h * 4 + 3] + bo, 0.f);
            *reinterpret_cast<float4*>(Op + base + h * 4) = v;
        }
    }
}

__global__ __launch_bounds__(256, 4)
void os_final2(const float* __restrict__ in, const float* __restrict__ w,
               const float* __restrict__ b, float* __restrict__ out)
{
    __shared__ float sx[32][260];
    int nb = blockIdx.x;                 // 256 blocks
    int n = nb >> 6, t0 = (nb & 63) * 256;
    int tid = threadIdx.x;
    float acc = b[0];
    for (int i0 = 0; i0 < 128; i0 += 32) {
        __syncthreads();
        for (int j = tid; j < 32 * 256; j += 256) {
            int ii = j >> 8, tt = j & 255;
            sx[ii][tt] = in[((size_t)(n * 128 + i0 + ii)) * T_LEN + t0 + tt];
        }
        __syncthreads();
        #pragma unroll
        for (int ii = 0; ii < 32; ii++) acc = fmaf(w[i0 + ii], sx[ii][tid], acc);
    }
    out[(size_t)n * T_LEN + t0 + tid] = tanhf(acc);
}

// ======================= launch =======================
extern "C" void kernel_launch(void* const* d_in, const int* in_sizes, int n_in,
                              void* d_out, int out_size, void* d_ws, size_t ws_size,
                              hipStream_t stream)
{
    (void)in_sizes; (void)n_in; (void)out_size; (void)ws_size;
    const float* mel    = (const float*)d_in[0];
    const float* in_w   = (const float*)d_in[1];
    const float* in_b   = (const float*)d_in[2];
    const float* pre_w  = (const float*)d_in[3];
    const float* pre_b  = (const float*)d_in[4];
    const float* up1_w  = (const float*)d_in[5];
    const float* up1_b  = (const float*)d_in[6];
    const float* up2_w  = (const float*)d_in[7];
    const float* up2_b  = (const float*)d_in[8];
    const float* wn_wsp = (const float*)d_in[9];
    const float* wn_bs  = (const float*)d_in[10];
    const float* sk_wsp = (const float*)d_in[11];
    const float* sk_bs  = (const float*)d_in[12];
    const float* o1w = (const float*)d_in[13];
    const float* o1b = (const float*)d_in[14];
    const float* o2w = (const float*)d_in[15];
    const float* o2b = (const float*)d_in[16];
    const float* o3w = (const float*)d_in[17];
    const float* o3b = (const float*)d_in[18];

    char* base = (char*)d_ws;
    unsigned short* XT0h = (unsigned short*)(base);               // 16,777,216 B
    unsigned short* XT0l = (unsigned short*)(base + 16777216);
    unsigned short* XT1h = (unsigned short*)(base + 33554432);
    unsigned short* XT1l = (unsigned short*)(base + 50331648);
    float* SK    = (float*)(base + 67108864);                     // 33,554,432 B
    unsigned short* Apk = (unsigned short*)(base + 100663296);    // 11,796,480 B
    unsigned short* Spk = (unsigned short*)(base + 112459776);    //  1,966,080 B
    float* pre_wT = (float*)(base + 114425856);                   //    983,040 B
    float* wup1T  = (float*)(base + 115408896);                   //    262,144 B
    float* wup2T  = (float*)(base + 115671040);                   //    262,144 B
    float* o1T    = (float*)(base + 115933184);                   //     65,536 B
    float* o2T    = (float*)(base + 115998720);                   //     65,536 B
    float* xf64   = (float*)(base + 116064256);                   //    131,072 B
    float* x256   = (float*)(base + 116195328);                   //    524,288 B
    float* x1024  = (float*)(base + 116719616);                   //  2,097,152 B
    float* X0 = (float*)(base + 33554432);   // alias XT1 region (dead after layers)
    float* X1 = (float*)(base);              // alias XT0 region

    prep_w2<<<1696, 256, 0, stream>>>(wn_wsp, sk_wsp, pre_w, up1_w, up2_w, o1w, o2w,
                                      Apk, Spk, pre_wT, wup1T, wup2T, o1T, o2T);

    fe_front<<<4, 512, 0, stream>>>(mel, in_w, in_b, pre_wT, pre_b, xf64);
    fe_up2<<<dim3(1, 4), 512, 0, stream>>>(xf64, x256, wup1T, up1_b, 64);
    fe_up2<<<dim3(4, 4), 512, 0, stream>>>(x256, x1024, wup2T, up2_b, 256);
    fe_repeat2<<<32768, 256, 0, stream>>>(x1024, XT0h, XT0l);
    zero_sk<<<8192, 256, 0, stream>>>((float4*)SK);

    for (int li = 0; li < 30; li++) {
        int d = 1 << (li % 10);
        const unsigned short* ih = (li & 1) ? XT1h : XT0h;
        const unsigned short* il = (li & 1) ? XT1l : XT0l;
        unsigned short* oh = (li & 1) ? XT0h : XT1h;
        unsigned short* ol = (li & 1) ? XT0l : XT1l;
        wn_layer<<<dim3(T_LEN / 128, 4), 256, 0, stream>>>(
            ih, il, oh, ol, SK,
            Apk + (size_t)li * 196608, wn_bs + li * 256,
            Spk + (size_t)li * 32768, sk_bs + li * 128, d);
    }

    os_conv<true><<<dim3(T_LEN / 64, 4), 256, 0, stream>>>(SK, X0, o1T, o1b);
    os_conv<false><<<dim3(T_LEN / 64, 4), 256, 0, stream>>>(X0, X1, o2T, o2b);
    os_final2<<<256, 256, 0, stream>>>(X1, o3w, o3b, (float*)d_out);
}

// Round 5
// 1935.344 us; speedup vs baseline: 2.1879x; 2.1879x over previous
//
#include <hip/hip_runtime.h>
#include <math.h>

#define LRELU 0.1f
#define SQRT_HALF 0.7071067811865476f

constexpr int T_LEN = 16384;

typedef __attribute__((ext_vector_type(8))) short short8;
typedef __attribute__((ext_vector_type(4))) float f32x4;

__device__ inline void bsplit(float v, unsigned short& hi, unsigned short& lo) {
    unsigned u = __float_as_uint(v);
    unsigned rh = (u + 0x7FFFu + ((u >> 16) & 1u)) >> 16;
    float fh = __uint_as_float(rh << 16);
    float r = v - fh;
    unsigned u2 = __float_as_uint(r);
    unsigned rl = (u2 + 0x7FFFu + ((u2 >> 16) & 1u)) >> 16;
    hi = (unsigned short)rh; lo = (unsigned short)rl;
}
__device__ inline float b2f(unsigned short s) { return __uint_as_float(((unsigned)s) << 16); }

// ======================= prep =======================
// Apk[li][ks 12][m16 16][h 2][lane 64][j 8] ; k = ks*32 + 4*(lane>>4)+(j&3)+16*(j>>2); tap=k>>7, i=k&127
// Spk[li][ks2 4][m8 8][h 2][lane 64][j 8]
// Opk1/Opk2: same as one Spk layer
__global__ void prep_w3(const float* __restrict__ wn_ws, const float* __restrict__ sk_ws,
                        const float* __restrict__ o1w, const float* __restrict__ o2w,
                        unsigned short* __restrict__ Apk, unsigned short* __restrict__ Spk,
                        unsigned short* __restrict__ Opk1, unsigned short* __restrict__ Opk2)
{
    int b = blockIdx.x, tid = threadIdx.x;
    if (b < 360) {                      // Apk: (li, ks)
        __shared__ float sl[256][32];
        int li = b / 12, ks = b % 12;
        int tap = ks >> 2, i0 = (ks & 3) * 32;
        for (int j = tid; j < 8192; j += 256) {
            int o = j >> 5, ii = j & 31;
            sl[o][ii] = wn_ws[((size_t)(li * 256 + o) * 128 + i0 + ii) * 3 + tap];
        }
        __syncthreads();
        size_t obase = ((size_t)(li * 12 + ks)) * 16384;
        for (int e = tid; e < 8192; e += 256) {
            int j = e & 7, l = (e >> 3) & 63, m16 = e >> 9;
            int o = m16 * 16 + (l & 15);
            int ii = 4 * (l >> 4) + (j & 3) + 16 * (j >> 2);
            unsigned short hi, lo; bsplit(sl[o][ii], hi, lo);
            Apk[obase + (size_t)m16 * 1024 + l * 8 + j] = hi;
            Apk[obase + (size_t)m16 * 1024 + 512 + l * 8 + j] = lo;
        }
    } else {                            // Spk (120 blocks) + Opk (8 blocks)
        __shared__ float s2[128][32];
        int bb = b - 360;
        const float* src; unsigned short* dst; int ks2;
        if (bb < 120) { int li = bb / 4; ks2 = bb % 4; src = sk_ws + (size_t)li * 16384; dst = Spk + ((size_t)(li * 4 + ks2)) * 8192; }
        else if (bb < 124) { ks2 = bb - 120; src = o1w; dst = Opk1 + (size_t)ks2 * 8192; }
        else { ks2 = bb - 124; src = o2w; dst = Opk2 + (size_t)ks2 * 8192; }
        int i0 = ks2 * 32;
        for (int j = tid; j < 4096; j += 256) {
            int o = j >> 5, ii = j & 31;
            s2[o][ii] = src[(size_t)o * 128 + i0 + ii];
        }
        __syncthreads();
        for (int e = tid; e < 4096; e += 256) {
            int j = e & 7, l = (e >> 3) & 63, m8 = e >> 9;
            int o = m8 * 16 + (l & 15);
            int ii = 4 * (l >> 4) + (j & 3) + 16 * (j >> 2);
            unsigned short hi, lo; bsplit(s2[o][ii], hi, lo);
            dst[(size_t)m8 * 1024 + l * 8 + j] = hi;
            dst[(size_t)m8 * 1024 + 512 + l * 8 + j] = lo;
        }
    }
}

// ======================= front end =======================
__global__ void fe_in(const float* __restrict__ mel, const float* __restrict__ w,
                      const float* __restrict__ b, float* __restrict__ out)
{
    __shared__ float mc[80];
    int t = blockIdx.x, n = blockIdx.y, o = threadIdx.x;
    if (o < 80) mc[o] = mel[(n * 80 + o) * 64 + t];
    __syncthreads();
    float acc = b[o];
    #pragma unroll 8
    for (int i = 0; i < 80; i++) acc = fmaf(w[o * 80 + i], mc[i], acc);
    out[((size_t)n * 128 + o) * 64 + t] = acc;
}

__global__ void fe_pre(const float* __restrict__ in, float* __restrict__ out,
                       const float* __restrict__ w, const float* __restrict__ b, int d)
{
    __shared__ float col[3][128];
    int t = blockIdx.x, n = blockIdx.y, o = threadIdx.x;
    #pragma unroll
    for (int s = 0; s < 3; s++) {
        int tt = t + (s - 1) * d;
        col[s][o] = ((unsigned)tt < 64u) ? in[(n * 128 + o) * 64 + tt] : 0.f;
    }
    __syncthreads();
    float acc = b[o];
    const float* wo = w + o * 384;
    #pragma unroll 4
    for (int i = 0; i < 128; i++) {
        acc = fmaf(wo[i * 3 + 0], col[0][i], acc);
        acc = fmaf(wo[i * 3 + 1], col[1][i], acc);
        acc = fmaf(wo[i * 3 + 2], col[2][i], acc);
    }
    float y = acc > 0.f ? acc : LRELU * acc;
    out[(n * 128 + o) * 64 + t] = (y + in[(n * 128 + o) * 64 + t]) * SQRT_HALF;
}

// transpose conv k=4 s=4; block: 16 q x all 128 o
__global__ __launch_bounds__(256, 4)
void fe_up3(const float* __restrict__ in, float* __restrict__ out,
            const float* __restrict__ w, const float* __restrict__ bias, int Lin)
{
    __shared__ float xs[128][16];
    const int n = blockIdx.y, qb = blockIdx.x * 16;
    const int tid = threadIdx.x;
    for (int j = tid; j < 2048; j += 256) {
        int i = j >> 4, qq = j & 15;
        xs[i][qq] = in[(size_t)(n * 128 + i) * Lin + qb + qq];
    }
    __syncthreads();
    const int o = tid & 127, qh = tid >> 7;
    float acc[8][4];
    #pragma unroll
    for (int q = 0; q < 8; q++)
        #pragma unroll
        for (int r = 0; r < 4; r++) acc[q][r] = 0.f;
    const float4* wo = (const float4*)(w + (size_t)o * 512);
    for (int i = 0; i < 128; i++) {
        float4 w4 = wo[i];
        #pragma unroll
        for (int q = 0; q < 8; q++) {
            float xv = xs[i][qh * 8 + q];
            acc[q][0] = fmaf(w4.w, xv, acc[q][0]);
            acc[q][1] = fmaf(w4.z, xv, acc[q][1]);
            acc[q][2] = fmaf(w4.y, xv, acc[q][2]);
            acc[q][3] = fmaf(w4.x, xv, acc[q][3]);
        }
    }
    float bo = bias[o];
    const int Lout = 4 * Lin;
    #pragma unroll
    for (int q = 0; q < 8; q++) {
        float4 v;
        float a0 = acc[q][0] + bo, a1 = acc[q][1] + bo, a2 = acc[q][2] + bo, a3 = acc[q][3] + bo;
        v.x = a0 > 0.f ? a0 : LRELU * a0;
        v.y = a1 > 0.f ? a1 : LRELU * a1;
        v.z = a2 > 0.f ? a2 : LRELU * a2;
        v.w = a3 > 0.f ? a3 : LRELU * a3;
        *(float4*)(out + (size_t)(n * 128 + o) * Lout + (size_t)(qb + qh * 8 + q) * 4) = v;
    }
}

// 16x repeat -> bf16 hi/lo planes [n][t][128]
__global__ void fe_repeat3(const float* __restrict__ x1024,
                           unsigned short* __restrict__ XTh, unsigned short* __restrict__ XTl)
{
    size_t idx = (size_t)blockIdx.x * 256 + threadIdx.x;   // 8,388,608
    int ch = (int)(idx & 127);
    int t = (int)((idx >> 7) & 16383);
    int n = (int)(idx >> 21);
    float v = x1024[((size_t)(n * 128 + ch)) * 1024 + (t >> 4)];
    unsigned short hi, lo; bsplit(v, hi, lo);
    XTh[idx] = hi; XTl[idx] = lo;
}

// ======================= WaveNet layer v3 =======================
__global__ __launch_bounds__(256, 2)
void wn_layer(const unsigned short* __restrict__ Xh, const unsigned short* __restrict__ Xl,
              unsigned short* __restrict__ Yh, unsigned short* __restrict__ Yl,
              const unsigned short* __restrict__ Apk, const float* __restrict__ gb,
              const unsigned short* __restrict__ Spk, const float* __restrict__ skb, int dil)
{
    __shared__ __align__(16) char ldsX[32768];   // [h/l 16KB][64 row][128 ch], XOR-swizzled 16B slots
    __shared__ __align__(16) char ldsG[32768];

    const int n = blockIdx.y, t0 = blockIdx.x * 64;
    const int tid = threadIdx.x, lane = tid & 63, wid = tid >> 6;
    const int tl = lane & 15, cb = 4 * (lane >> 4);
    const size_t nbase = (size_t)n * T_LEN;

    f32x4 acc[4][4];
    const f32x4 z4 = {0.f, 0.f, 0.f, 0.f};
    #pragma unroll
    for (int mf = 0; mf < 4; mf++)
        #pragma unroll
        for (int nf = 0; nf < 4; nf++) acc[mf][nf] = z4;

    const int m16c[4] = {2 * wid, 2 * wid + 1, 8 + 2 * wid, 9 + 2 * wid};
    const short8* ap = (const short8*)Apk;
    const int sord[3] = {0, 2, 1};    // center shift LAST: ldsX then holds x_in at epilogue

    for (int si = 0; si < 3; si++) {
        const int s = sord[si];
        const int tsh = t0 + (s - 1) * dil;
        __syncthreads();
        for (int j = tid; j < 2048; j += 256) {
            int p = j >> 10, jj = j & 1023, row = jj >> 4, slot = jj & 15;
            int t = tsh + row;
            uint4 v = make_uint4(0u, 0u, 0u, 0u);
            if ((unsigned)t < (unsigned)T_LEN) {
                const unsigned short* src = (p ? Xl : Xh) + (nbase + t) * 128 + slot * 8;
                v = *(const uint4*)src;
            }
            *(uint4*)(ldsX + p * 16384 + row * 256 + ((slot ^ (row & 7)) << 4)) = v;
        }
        __syncthreads();
        for (int c = 0; c < 4; c++) {
            const int ks = s * 4 + c, i0 = c * 32;
            short8 Ah[4], Al[4];
            #pragma unroll
            for (int mf = 0; mf < 4; mf++) {
                int ib = (ks * 16 + m16c[mf]) * 128 + lane;
                Ah[mf] = ap[ib];
                Al[mf] = ap[ib + 64];
            }
            #pragma unroll
            for (int nf = 0; nf < 4; nf++) {
                int row = nf * 16 + tl, swz = (row & 7) << 4;
                const char* rb = ldsX + row * 256;
                int c1 = ((i0 + cb) * 2) ^ swz;
                int c2 = ((i0 + cb + 16) * 2) ^ swz;
                union { short8 s8; uint2 u[2]; } Bh, Bl;
                Bh.u[0] = *(const uint2*)(rb + c1);
                Bh.u[1] = *(const uint2*)(rb + c2);
                Bl.u[0] = *(const uint2*)(rb + 16384 + c1);
                Bl.u[1] = *(const uint2*)(rb + 16384 + c2);
                #pragma unroll
                for (int mf = 0; mf < 4; mf++) {
                    acc[mf][nf] = __builtin_amdgcn_mfma_f32_16x16x32_bf16(Ah[mf], Bh.s8, acc[mf][nf], 0, 0, 0);
                    acc[mf][nf] = __builtin_amdgcn_mfma_f32_16x16x32_bf16(Al[mf], Bh.s8, acc[mf][nf], 0, 0, 0);
                    acc[mf][nf] = __builtin_amdgcn_mfma_f32_16x16x32_bf16(Ah[mf], Bl.s8, acc[mf][nf], 0, 0, 0);
                }
            }
        }
    }

    // ---- gating -> ldsG ([t][ch] bf16 pairs, same swizzle) ----
    float bt[2][4], bsg[2][4];
    #pragma unroll
    for (int mf2 = 0; mf2 < 2; mf2++)
        #pragma unroll
        for (int r = 0; r < 4; r++) {
            int ch = (2 * wid + mf2) * 16 + cb + r;
            bt[mf2][r] = gb[ch];
            bsg[mf2][r] = gb[128 + ch];
        }
    #pragma unroll
    for (int mf2 = 0; mf2 < 2; mf2++) {
        #pragma unroll
        for (int nf = 0; nf < 4; nf++) {
            unsigned hs[4], ls[4];
            #pragma unroll
            for (int r = 0; r < 4; r++) {
                float g1 = acc[mf2][nf][r] + bt[mf2][r];
                float g2 = acc[mf2 + 2][nf][r] + bsg[mf2][r];
                float gv = tanhf(g1) * (1.f / (1.f + expf(-g2)));
                unsigned short hi, lo; bsplit(gv, hi, lo);
                hs[r] = hi; ls[r] = lo;
            }
            int row = nf * 16 + tl, swz = (row & 7) << 4;
            int cB = (((2 * wid + mf2) * 16 + cb) * 2) ^ swz;
            uint2 hv = make_uint2(hs[0] | (hs[1] << 16), hs[2] | (hs[3] << 16));
            uint2 lv = make_uint2(ls[0] | (ls[1] << 16), ls[2] | (ls[3] << 16));
            *(uint2*)(ldsG + row * 256 + cB) = hv;
            *(uint2*)(ldsG + 16384 + row * 256 + cB) = lv;
        }
    }
    __syncthreads();

    // ---- skip GEMM ----
    f32x4 acc2[2][4];
    #pragma unroll
    for (int mf2 = 0; mf2 < 2; mf2++)
        #pragma unroll
        for (int nf = 0; nf < 4; nf++) acc2[mf2][nf] = z4;
    const short8* sp = (const short8*)Spk;
    #pragma unroll
    for (int ks2 = 0; ks2 < 4; ks2++) {
        const int i0 = ks2 * 32;
        short8 A2h[2], A2l[2];
        #pragma unroll
        for (int mf2 = 0; mf2 < 2; mf2++) {
            int ib = (ks2 * 8 + 2 * wid + mf2) * 128 + lane;
            A2h[mf2] = sp[ib];
            A2l[mf2] = sp[ib + 64];
        }
        #pragma unroll
        for (int nf = 0; nf < 4; nf++) {
            int row = nf * 16 + tl, swz = (row & 7) << 4;
            const char* rb = ldsG + row * 256;
            int c1 = ((i0 + cb) * 2) ^ swz;
            int c2 = ((i0 + cb + 16) * 2) ^ swz;
            union { short8 s8; uint2 u[2]; } Bh, Bl;
            Bh.u[0] = *(const uint2*)(rb + c1);
            Bh.u[1] = *(const uint2*)(rb + c2);
            Bl.u[0] = *(const uint2*)(rb + 16384 + c1);
            Bl.u[1] = *(const uint2*)(rb + 16384 + c2);
            #pragma unroll
            for (int mf2 = 0; mf2 < 2; mf2++) {
                acc2[mf2][nf] = __builtin_amdgcn_mfma_f32_16x16x32_bf16(A2h[mf2], Bh.s8, acc2[mf2][nf], 0, 0, 0);
                acc2[mf2][nf] = __builtin_amdgcn_mfma_f32_16x16x32_bf16(A2l[mf2], Bh.s8, acc2[mf2][nf], 0, 0, 0);
                acc2[mf2][nf] = __builtin_amdgcn_mfma_f32_16x16x32_bf16(A2h[mf2], Bl.s8, acc2[mf2][nf], 0, 0, 0);
            }
        }
    }

    // ---- y = s + x_in (residual from ldsX center tile), bf16-split in regs ----
    uint2 yh[2][4], yl[2][4];
    #pragma unroll
    for (int mf2 = 0; mf2 < 2; mf2++) {
        const int ch0 = (2 * wid + mf2) * 16 + cb;
        float bo[4];
        #pragma unroll
        for (int r = 0; r < 4; r++) bo[r] = skb[ch0 + r];
        #pragma unroll
        for (int nf = 0; nf < 4; nf++) {
            int row = nf * 16 + tl, swz = (row & 7) << 4;
            int cB = (ch0 * 2) ^ swz;
            union { uint2 u; unsigned short s[4]; } xh2, xl2;
            xh2.u = *(const uint2*)(ldsX + row * 256 + cB);
            xl2.u = *(const uint2*)(ldsX + 16384 + row * 256 + cB);
            unsigned hs[4], ls[4];
            #pragma unroll
            for (int r = 0; r < 4; r++) {
                float xin = b2f(xh2.s[r]) + b2f(xl2.s[r]);
                float sv = acc2[mf2][nf][r] + bo[r];
                float y = sv + xin;
                unsigned short hi, lo; bsplit(y, hi, lo);
                hs[r] = hi; ls[r] = lo;
            }
            yh[mf2][nf] = make_uint2(hs[0] | (hs[1] << 16), hs[2] | (hs[3] << 16));
            yl[mf2][nf] = make_uint2(ls[0] | (ls[1] << 16), ls[2] | (ls[3] << 16));
        }
    }
    __syncthreads();
    #pragma unroll
    for (int mf2 = 0; mf2 < 2; mf2++) {
        const int ch0 = (2 * wid + mf2) * 16 + cb;
        #pragma unroll
        for (int nf = 0; nf < 4; nf++) {
            int row = nf * 16 + tl, swz = (row & 7) << 4;
            int cB = (ch0 * 2) ^ swz;
            *(uint2*)(ldsG + row * 256 + cB) = yh[mf2][nf];
            *(uint2*)(ldsG + 16384 + row * 256 + cB) = yl[mf2][nf];
        }
    }
    __syncthreads();
    for (int j = tid; j < 2048; j += 256) {
        int p = j >> 10, jj = j & 1023, row = jj >> 4, slot = jj & 15;
        uint4 v = *(const uint4*)(ldsG + p * 16384 + row * 256 + ((slot ^ (row & 7)) << 4));
        unsigned short* dst = (p ? Yl : Yh) + (nbase + t0 + row) * 128 + slot * 8;
        *(uint4*)dst = v;
    }
}

// ======================= fused output stack =======================
__global__ __launch_bounds__(256, 2)
void os_fused(const unsigned short* __restrict__ Fh, const unsigned short* __restrict__ Fl,
              const unsigned short* __restrict__ Ih, const unsigned short* __restrict__ Il,
              const unsigned short* __restrict__ Opk1, const float* __restrict__ o1b,
              const unsigned short* __restrict__ Opk2, const float* __restrict__ o2b,
              const float* __restrict__ o3w, const float* __restrict__ o3b,
              float* __restrict__ out)
{
    __shared__ __align__(16) char ldsA[32768];
    __shared__ __align__(16) char ldsB[32768];
    const int n = blockIdx.y, t0 = blockIdx.x * 64;
    const int tid = threadIdx.x, lane = tid & 63, wid = tid >> 6;
    const int tl = lane & 15, cb = 4 * (lane >> 4);
    const f32x4 z4 = {0.f, 0.f, 0.f, 0.f};

    // P1: relu(xfin - xinit) -> bf16 pairs in ldsA
    for (int j = tid; j < 1024; j += 256) {
        int row = j >> 4, slot = j & 15;
        size_t g = ((size_t)n * T_LEN + t0 + row) * 128 + slot * 8;
        union { uint4 v; unsigned short s[8]; } fh, fl, ih, il, ho, lo_;
        fh.v = *(const uint4*)(Fh + g);
        fl.v = *(const uint4*)(Fl + g);
        ih.v = *(const uint4*)(Ih + g);
        il.v = *(const uint4*)(Il + g);
        #pragma unroll
        for (int e = 0; e < 8; e++) {
            float d = (b2f(fh.s[e]) + b2f(fl.s[e])) - (b2f(ih.s[e]) + b2f(il.s[e]));
            d = fmaxf(d, 0.f);
            unsigned short hi, lo; bsplit(d, hi, lo);
            ho.s[e] = hi; lo_.s[e] = lo;
        }
        int off = row * 256 + ((slot ^ (row & 7)) << 4);
        *(uint4*)(ldsA + off) = ho.v;
        *(uint4*)(ldsA + 16384 + off) = lo_.v;
    }
    __syncthreads();

    // P2: GEMM1 (ldsA -> relu -> pairs in ldsB)
    {
        f32x4 acc[2][4];
        #pragma unroll
        for (int mf2 = 0; mf2 < 2; mf2++)
            #pragma unroll
            for (int nf = 0; nf < 4; nf++) acc[mf2][nf] = z4;
        const short8* op = (const short8*)Opk1;
        #pragma unroll
        for (int ks2 = 0; ks2 < 4; ks2++) {
            const int i0 = ks2 * 32;
            short8 Ah[2], Al[2];
            #pragma unroll
            for (int mf2 = 0; mf2 < 2; mf2++) {
                int ib = (ks2 * 8 + 2 * wid + mf2) * 128 + lane;
                Ah[mf2] = op[ib]; Al[mf2] = op[ib + 64];
            }
            #pragma unroll
            for (int nf = 0; nf < 4; nf++) {
                int row = nf * 16 + tl, swz = (row & 7) << 4;
                const char* rb = ldsA + row * 256;
                int c1 = ((i0 + cb) * 2) ^ swz;
                int c2 = ((i0 + cb + 16) * 2) ^ swz;
                union { short8 s8; uint2 u[2]; } Bh, Bl;
                Bh.u[0] = *(const uint2*)(rb + c1);
                Bh.u[1] = *(const uint2*)(rb + c2);
                Bl.u[0] = *(const uint2*)(rb + 16384 + c1);
                Bl.u[1] = *(const uint2*)(rb + 16384 + c2);
                #pragma unroll
                for (int mf2 = 0; mf2 < 2; mf2++) {
                    acc[mf2][nf] = __builtin_amdgcn_mfma_f32_16x16x32_bf16(Ah[mf2], Bh.s8, acc[mf2][nf], 0, 0, 0);
                    acc[mf2][nf] = __builtin_amdgcn_mfma_f32_16x16x32_bf16(Al[mf2], Bh.s8, acc[mf2][nf], 0, 0, 0);
                    acc[mf2][nf] = __builtin_amdgcn_mfma_f32_16x16x32_bf16(Ah[mf2], Bl.s8, acc[mf2][nf], 0, 0, 0);
                }
            }
        }
        #pragma unroll
        for (int mf2 = 0; mf2 < 2; mf2++) {
            const int ch0 = (2 * wid + mf2) * 16 + cb;
            #pragma unroll
            for (int nf = 0; nf < 4; nf++) {
                unsigned hs[4], ls[4];
                #pragma unroll
                for (int r = 0; r < 4; r++) {
                    float v = fmaxf(acc[mf2][nf][r] + o1b[ch0 + r], 0.f);
                    unsigned short hi, lo; bsplit(v, hi, lo);
                    hs[r] = hi; ls[r] = lo;
                }
                int row = nf * 16 + tl, swz = (row & 7) << 4;
                int cB = (ch0 * 2) ^ swz;
                *(uint2*)(ldsB + row * 256 + cB) = make_uint2(hs[0] | (hs[1] << 16), hs[2] | (hs[3] << 16));
                *(uint2*)(ldsB + 16384 + row * 256 + cB) = make_uint2(ls[0] | (ls[1] << 16), ls[2] | (ls[3] << 16));
            }
        }
    }
    __syncthreads();

    // P3: GEMM2 (ldsB -> relu -> f32 tile in ldsA)
    {
        f32x4 acc[2][4];
        #pragma unroll
        for (int mf2 = 0; mf2 < 2; mf2++)
            #pragma unroll
            for (int nf = 0; nf < 4; nf++) acc[mf2][nf] = z4;
        const short8* op = (const short8*)Opk2;
        #pragma unroll
        for (int ks2 = 0; ks2 < 4; ks2++) {
            const int i0 = ks2 * 32;
            short8 Ah[2], Al[2];
            #pragma unroll
            for (int mf2 = 0; mf2 < 2; mf2++) {
                int ib = (ks2 * 8 + 2 * wid + mf2) * 128 + lane;
                Ah[mf2] = op[ib]; Al[mf2] = op[ib + 64];
            }
            #pragma unroll
            for (int nf = 0; nf < 4; nf++) {
                int row = nf * 16 + tl, swz = (row & 7) << 4;
                const char* rb = ldsB + row * 256;
                int c1 = ((i0 + cb) * 2) ^ swz;
                int c2 = ((i0 + cb + 16) * 2) ^ swz;
                union { short8 s8; uint2 u[2]; } Bh, Bl;
                Bh.u[0] = *(const uint2*)(rb + c1);
                Bh.u[1] = *(const uint2*)(rb + c2);
                Bl.u[0] = *(const uint2*)(rb + 16384 + c1);
                Bl.u[1] = *(const uint2*)(rb + 16384 + c2);
                #pragma unroll
                for (int mf2 = 0; mf2 < 2; mf2++) {
                    acc[mf2][nf] = __builtin_amdgcn_mfma_f32_16x16x32_bf16(Ah[mf2], Bh.s8, acc[mf2][nf], 0, 0, 0);
                    acc[mf2][nf] = __builtin_amdgcn_mfma_f32_16x16x32_bf16(Al[mf2], Bh.s8, acc[mf2][nf], 0, 0, 0);
                    acc[mf2][nf] = __builtin_amdgcn_mfma_f32_16x16x32_bf16(Ah[mf2], Bl.s8, acc[mf2][nf], 0, 0, 0);
                }
            }
        }
        __syncthreads();   // all reads of ldsA (P2) done; safe to overwrite as f32 tile
        #pragma unroll
        for (int mf2 = 0; mf2 < 2; mf2++) {
            const int ch0 = (2 * wid + mf2) * 16 + cb;
            #pragma unroll
            for (int nf = 0; nf < 4; nf++) {
                int row = nf * 16 + tl, swz = (row & 7) << 4;
                float4 v;
                v.x = fmaxf(acc[mf2][nf][0] + o2b[ch0 + 0], 0.f);
                v.y = fmaxf(acc[mf2][nf][1] + o2b[ch0 + 1], 0.f);
                v.z = fmaxf(acc[mf2][nf][2] + o2b[ch0 + 2], 0.f);
                v.w = fmaxf(acc[mf2][nf][3] + o2b[ch0 + 3], 0.f);
                *(float4*)(ldsA + row * 512 + ((ch0 * 4) ^ swz)) = v;
            }
        }
    }
    __syncthreads();

    // P4: final 1-ch conv + tanh
    {
        const int t_loc = tid >> 2, qq = tid & 3;
        const int row = t_loc, swz = (row & 7) << 4;
        float a = 0.f;
        #pragma unroll
        for (int cc = 0; cc < 8; cc++) {
            int ch = qq * 32 + cc * 4;
            float4 v = *(const float4*)(ldsA + row * 512 + ((ch * 4) ^ swz));
            a += o3w[ch] * v.x + o3w[ch + 1] * v.y + o3w[ch + 2] * v.z + o3w[ch + 3] * v.w;
        }
        a += __shfl_xor(a, 1);
        a += __shfl_xor(a, 2);
        if (qq == 0) out[(size_t)n * T_LEN + t0 + t_loc] = tanhf(a + o3b[0]);
    }
}

// ======================= launch =======================
extern "C" void kernel_launch(void* const* d_in, const int* in_sizes, int n_in,
                              void* d_out, int out_size, void* d_ws, size_t ws_size,
                              hipStream_t stream)
{
    (void)in_sizes; (void)n_in; (void)out_size; (void)ws_size;
    const float* mel    = (const float*)d_in[0];
    const float* in_w   = (const float*)d_in[1];
    const float* in_b   = (const float*)d_in[2];
    const float* pre_w  = (const float*)d_in[3];
    const float* pre_b  = (const float*)d_in[4];
    const float* up1_w  = (const float*)d_in[5];
    const float* up1_b  = (const float*)d_in[6];
    const float* up2_w  = (const float*)d_in[7];
    const float* up2_b  = (const float*)d_in[8];
    const float* wn_wsp = (const float*)d_in[9];
    const float* wn_bs  = (const float*)d_in[10];
    const float* sk_wsp = (const float*)d_in[11];
    const float* sk_bs  = (const float*)d_in[12];
    const float* o1w = (const float*)d_in[13];
    const float* o1b = (const float*)d_in[14];
    const float* o2w = (const float*)d_in[15];
    const float* o2b = (const float*)d_in[16];
    const float* o3w = (const float*)d_in[17];
    const float* o3b = (const float*)d_in[18];

    // each bf16 plane: 4*16384*128 elements = 8,388,608 elems = 16,777,216 BYTES
    char* base = (char*)d_ws;
    unsigned short* XAh = (unsigned short*)(base);
    unsigned short* XAl = (unsigned short*)(base + 16777216);
    unsigned short* XBh = (unsigned short*)(base + 33554432);
    unsigned short* XBl = (unsigned short*)(base + 50331648);
    unsigned short* XCh = (unsigned short*)(base + 67108864);
    unsigned short* XCl = (unsigned short*)(base + 83886080);
    unsigned short* Apk = (unsigned short*)(base + 100663296);   // 11,796,480 B
    unsigned short* Spk = (unsigned short*)(base + 112459776);   //  1,966,080 B
    unsigned short* Opk1 = (unsigned short*)(base + 114425856);  //     65,536 B
    unsigned short* Opk2 = (unsigned short*)(base + 114491392);  //     65,536 B
    float* a64   = (float*)(base + 114556928);                   //    131,072 B
    float* b64   = (float*)(base + 114688000);                   //    131,072 B
    float* x256  = (float*)(base + 114819072);                   //    524,288 B
    float* x1024 = (float*)(base + 115343360);                   //  2,097,152 B

    prep_w3<<<488, 256, 0, stream>>>(wn_wsp, sk_wsp, o1w, o2w, Apk, Spk, Opk1, Opk2);

    fe_in<<<dim3(64, 4), 128, 0, stream>>>(mel, in_w, in_b, a64);
    fe_pre<<<dim3(64, 4), 128, 0, stream>>>(a64, b64, pre_w + 0 * 49152, pre_b + 0 * 128, 1);
    fe_pre<<<dim3(64, 4), 128, 0, stream>>>(b64, a64, pre_w + 1 * 49152, pre_b + 1 * 128, 2);
    fe_pre<<<dim3(64, 4), 128, 0, stream>>>(a64, b64, pre_w + 2 * 49152, pre_b + 2 * 128, 4);
    fe_pre<<<dim3(64, 4), 128, 0, stream>>>(b64, a64, pre_w + 3 * 49152, pre_b + 3 * 128, 8);
    fe_pre<<<dim3(64, 4), 128, 0, stream>>>(a64, b64, pre_w + 4 * 49152, pre_b + 4 * 128, 16);
    fe_up3<<<dim3(4, 4), 256, 0, stream>>>(b64, x256, up1_w, up1_b, 64);
    fe_up3<<<dim3(16, 4), 256, 0, stream>>>(x256, x1024, up2_w, up2_b, 256);
    fe_repeat3<<<32768, 256, 0, stream>>>(x1024, XAh, XAl);

    for (int li = 0; li < 30; li++) {
        int d = 1 << (li % 10);
        const unsigned short *ih, *il; unsigned short *oh, *ol;
        if (li == 0)      { ih = XAh; il = XAl; oh = XBh; ol = XBl; }
        else if (li & 1)  { ih = XBh; il = XBl; oh = XCh; ol = XCl; }
        else              { ih = XCh; il = XCl; oh = XBh; ol = XBl; }
        wn_layer<<<dim3(T_LEN / 64, 4), 256, 0, stream>>>(
            ih, il, oh, ol,
            Apk + (size_t)li * 196608, wn_bs + li * 256,
            Spk + (size_t)li * 32768, sk_bs + li * 128, d);
    }

    // skips = x_final - x_init  (identity: x_{l+1} = x_l + s_l)
    os_fused<<<dim3(T_LEN / 64, 4), 256, 0, stream>>>(
        XCh, XCl, XAh, XAl, Opk1, o1b, Opk2, o2b, o3w, o3b, (float*)d_out);
}

// Round 6
// 1729.962 us; speedup vs baseline: 2.4476x; 1.1187x over previous
//
#include <hip/hip_runtime.h>
#include <math.h>

#define LRELU 0.1f
#define SQRT_HALF 0.7071067811865476f

constexpr int T_LEN = 16384;

typedef __attribute__((ext_vector_type(8))) short short8;
typedef __attribute__((ext_vector_type(4))) float f32x4;

union U4S8 { uint4 v; short8 s8; unsigned short us[8]; };

__device__ inline void bsplit(float v, unsigned short& hi, unsigned short& lo) {
    unsigned u = __float_as_uint(v);
    unsigned rh = (u + 0x7FFFu + ((u >> 16) & 1u)) >> 16;
    float fh = __uint_as_float(rh << 16);
    float r = v - fh;
    unsigned u2 = __float_as_uint(r);
    unsigned rl = (u2 + 0x7FFFu + ((u2 >> 16) & 1u)) >> 16;
    hi = (unsigned short)rh; lo = (unsigned short)rl;
}
__device__ inline float b2f(unsigned short s) { return __uint_as_float(((unsigned)s) << 16); }

// frag-tile uint4 index: Xf[n][tb][c][lane] (16B per lane)
__device__ inline size_t fidx(int n, int tb, int c, int l) {
    return ((size_t)((n << 10) + tb) * 4 + c) * 64 + l;
}

// fast gated activation: tanh(g1)*sigmoid(g2) via v_exp/v_rcp
__device__ inline float fast_gate(float g1, float g2) {
    float ax = fabsf(g1);
    float e = __expf(ax + ax);
    float th = 1.f - 2.f * __builtin_amdgcn_rcpf(e + 1.f);
    th = __uint_as_float(__float_as_uint(th) | (__float_as_uint(g1) & 0x80000000u));
    float sg = __builtin_amdgcn_rcpf(1.f + __expf(-g2));
    return th * sg;
}

// ======================= prep (unchanged frag k-mapping) =======================
__global__ void prep_w3(const float* __restrict__ wn_ws, const float* __restrict__ sk_ws,
                        const float* __restrict__ o1w, const float* __restrict__ o2w,
                        unsigned short* __restrict__ Apk, unsigned short* __restrict__ Spk,
                        unsigned short* __restrict__ Opk1, unsigned short* __restrict__ Opk2)
{
    int b = blockIdx.x, tid = threadIdx.x;
    if (b < 360) {
        __shared__ float sl[256][32];
        int li = b / 12, ks = b % 12;
        int tap = ks >> 2, i0 = (ks & 3) * 32;
        for (int j = tid; j < 8192; j += 256) {
            int o = j >> 5, ii = j & 31;
            sl[o][ii] = wn_ws[((size_t)(li * 256 + o) * 128 + i0 + ii) * 3 + tap];
        }
        __syncthreads();
        size_t obase = ((size_t)(li * 12 + ks)) * 16384;
        for (int e = tid; e < 8192; e += 256) {
            int j = e & 7, l = (e >> 3) & 63, m16 = e >> 9;
            int o = m16 * 16 + (l & 15);
            int ii = 4 * (l >> 4) + (j & 3) + 16 * (j >> 2);
            unsigned short hi, lo; bsplit(sl[o][ii], hi, lo);
            Apk[obase + (size_t)m16 * 1024 + l * 8 + j] = hi;
            Apk[obase + (size_t)m16 * 1024 + 512 + l * 8 + j] = lo;
        }
    } else {
        __shared__ float s2[128][32];
        int bb = b - 360;
        const float* src; unsigned short* dst; int ks2;
        if (bb < 120) { int li = bb / 4; ks2 = bb % 4; src = sk_ws + (size_t)li * 16384; dst = Spk + ((size_t)(li * 4 + ks2)) * 8192; }
        else if (bb < 124) { ks2 = bb - 120; src = o1w; dst = Opk1 + (size_t)ks2 * 8192; }
        else { ks2 = bb - 124; src = o2w; dst = Opk2 + (size_t)ks2 * 8192; }
        int i0 = ks2 * 32;
        for (int j = tid; j < 4096; j += 256) {
            int o = j >> 5, ii = j & 31;
            s2[o][ii] = src[(size_t)o * 128 + i0 + ii];
        }
        __syncthreads();
        for (int e = tid; e < 4096; e += 256) {
            int j = e & 7, l = (e >> 3) & 63, m8 = e >> 9;
            int o = m8 * 16 + (l & 15);
            int ii = 4 * (l >> 4) + (j & 3) + 16 * (j >> 2);
            unsigned short hi, lo; bsplit(s2[o][ii], hi, lo);
            dst[(size_t)m8 * 1024 + l * 8 + j] = hi;
            dst[(size_t)m8 * 1024 + 512 + l * 8 + j] = lo;
        }
    }
}

// ======================= front end (unchanged) =======================
__global__ void fe_in(const float* __restrict__ mel, const float* __restrict__ w,
                      const float* __restrict__ b, float* __restrict__ out)
{
    __shared__ float mc[80];
    int t = blockIdx.x, n = blockIdx.y, o = threadIdx.x;
    if (o < 80) mc[o] = mel[(n * 80 + o) * 64 + t];
    __syncthreads();
    float acc = b[o];
    #pragma unroll 8
    for (int i = 0; i < 80; i++) acc = fmaf(w[o * 80 + i], mc[i], acc);
    out[((size_t)n * 128 + o) * 64 + t] = acc;
}

__global__ void fe_pre(const float* __restrict__ in, float* __restrict__ out,
                       const float* __restrict__ w, const float* __restrict__ b, int d)
{
    __shared__ float col[3][128];
    int t = blockIdx.x, n = blockIdx.y, o = threadIdx.x;
    #pragma unroll
    for (int s = 0; s < 3; s++) {
        int tt = t + (s - 1) * d;
        col[s][o] = ((unsigned)tt < 64u) ? in[(n * 128 + o) * 64 + tt] : 0.f;
    }
    __syncthreads();
    float acc = b[o];
    const float* wo = w + o * 384;
    #pragma unroll 4
    for (int i = 0; i < 128; i++) {
        acc = fmaf(wo[i * 3 + 0], col[0][i], acc);
        acc = fmaf(wo[i * 3 + 1], col[1][i], acc);
        acc = fmaf(wo[i * 3 + 2], col[2][i], acc);
    }
    float y = acc > 0.f ? acc : LRELU * acc;
    out[(n * 128 + o) * 64 + t] = (y + in[(n * 128 + o) * 64 + t]) * SQRT_HALF;
}

__global__ __launch_bounds__(256, 4)
void fe_up3(const float* __restrict__ in, float* __restrict__ out,
            const float* __restrict__ w, const float* __restrict__ bias, int Lin)
{
    __shared__ float xs[128][16];
    const int n = blockIdx.y, qb = blockIdx.x * 16;
    const int tid = threadIdx.x;
    for (int j = tid; j < 2048; j += 256) {
        int i = j >> 4, qq = j & 15;
        xs[i][qq] = in[(size_t)(n * 128 + i) * Lin + qb + qq];
    }
    __syncthreads();
    const int o = tid & 127, qh = tid >> 7;
    float acc[8][4];
    #pragma unroll
    for (int q = 0; q < 8; q++)
        #pragma unroll
        for (int r = 0; r < 4; r++) acc[q][r] = 0.f;
    const float4* wo = (const float4*)(w + (size_t)o * 512);
    for (int i = 0; i < 128; i++) {
        float4 w4 = wo[i];
        #pragma unroll
        for (int q = 0; q < 8; q++) {
            float xv = xs[i][qh * 8 + q];
            acc[q][0] = fmaf(w4.w, xv, acc[q][0]);
            acc[q][1] = fmaf(w4.z, xv, acc[q][1]);
            acc[q][2] = fmaf(w4.y, xv, acc[q][2]);
            acc[q][3] = fmaf(w4.x, xv, acc[q][3]);
        }
    }
    float bo = bias[o];
    const int Lout = 4 * Lin;
    #pragma unroll
    for (int q = 0; q < 8; q++) {
        float4 v;
        float a0 = acc[q][0] + bo, a1 = acc[q][1] + bo, a2 = acc[q][2] + bo, a3 = acc[q][3] + bo;
        v.x = a0 > 0.f ? a0 : LRELU * a0;
        v.y = a1 > 0.f ? a1 : LRELU * a1;
        v.z = a2 > 0.f ? a2 : LRELU * a2;
        v.w = a3 > 0.f ? a3 : LRELU * a3;
        *(float4*)(out + (size_t)(n * 128 + o) * Lout + (size_t)(qb + qh * 8 + q) * 4) = v;
    }
}

// 16x repeat into frag-tile bf16 hi/lo planes
__global__ void fe_repeat_f(const float* __restrict__ x1024,
                            uint4* __restrict__ Xh, uint4* __restrict__ Xl)
{
    __shared__ float sx[128][65];
    const int n = blockIdx.y, tbq = blockIdx.x;   // grid (16, 4): 64 tb per block
    const int tid = threadIdx.x;
    for (int j = tid; j < 8192; j += 256) {
        int ch = j >> 6, col = j & 63;
        sx[ch][col] = x1024[(size_t)(n * 128 + ch) * 1024 + tbq * 64 + col];
    }
    __syncthreads();
    for (int m = tid; m < 16384; m += 256) {
        int l = m & 63, c = (m >> 6) & 3, tbr = m >> 8;
        U4S8 ho, lo_;
        #pragma unroll
        for (int j = 0; j < 8; j++) {
            int ch = 32 * c + 4 * (l >> 4) + (j & 3) + 16 * (j >> 2);
            unsigned short hi, lo; bsplit(sx[ch][tbr], hi, lo);
            ho.us[j] = hi; lo_.us[j] = lo;
        }
        size_t gi = fidx(n, tbq * 64 + tbr, c, l);
        Xh[gi] = ho.v; Xl[gi] = lo_.v;
    }
}

// ======================= WaveNet layer v4 (frag-tile, direct/staged) =======================
__global__ __launch_bounds__(256, 2)
void wn_layer(const uint4* __restrict__ Xh, const uint4* __restrict__ Xl,
              uint4* __restrict__ Yh, uint4* __restrict__ Yl,
              const unsigned short* __restrict__ Apk, const float* __restrict__ gb,
              const unsigned short* __restrict__ Spk, const float* __restrict__ skb, int dil)
{
    __shared__ __align__(16) uint4 S[2048];   // 32KB: [plane][nf][c][lane]

    const int n = blockIdx.y, tb0 = blockIdx.x * 4, t0 = tb0 * 16;
    const int tid = threadIdx.x, lane = tid & 63, wid = tid >> 6;
    const bool direct = (dil >= 16);
    const int dq = dil >> 4;

    f32x4 acc[4][4];
    const f32x4 z4 = {0.f, 0.f, 0.f, 0.f};
    #pragma unroll
    for (int mf = 0; mf < 4; mf++)
        #pragma unroll
        for (int nf = 0; nf < 4; nf++) acc[mf][nf] = z4;

    uint4 xch[4], xcl[4];
    const short8* ap = (const short8*)Apk;
    const int m16c[4] = {2 * wid, 2 * wid + 1, 8 + 2 * wid, 9 + 2 * wid};

    for (int s = 0; s < 3; s++) {
        if (!direct) {
            const int sh = (s - 1) * dil;
            __syncthreads();
            for (int j = tid; j < 1024; j += 256) {
                int l = j & 63, c = (j >> 6) & 3, nf = j >> 8;
                int t = t0 + nf * 16 + (l & 15) + sh;
                uint4 vh = make_uint4(0u, 0u, 0u, 0u), vl = vh;
                if ((unsigned)t < (unsigned)T_LEN) {
                    size_t gi = fidx(n, t >> 4, c, (l & 48) | (t & 15));
                    vh = Xh[gi]; vl = Xl[gi];
                }
                S[j] = vh; S[1024 + j] = vl;
            }
            __syncthreads();
        }
        const int tbS = tb0 + (s - 1) * dq;
        for (int c = 0; c < 4; c++) {
            const int ks = s * 4 + c;
            short8 Ah[4], Al[4];
            #pragma unroll
            for (int mf = 0; mf < 4; mf++) {
                int ib = (ks * 16 + m16c[mf]) * 128 + lane;
                Ah[mf] = ap[ib];
                Al[mf] = ap[ib + 64];
            }
            #pragma unroll
            for (int nf = 0; nf < 4; nf++) {
                U4S8 bh, bl;
                bool ok = true;
                if (direct) {
                    int tb = tbS + nf;
                    ok = ((unsigned)tb < 1024u);
                    if (ok) {
                        size_t gi = fidx(n, tb, c, lane);
                        bh.v = Xh[gi]; bl.v = Xl[gi];
                    }
                } else {
                    bh.v = S[(nf * 4 + c) * 64 + lane];
                    bl.v = S[1024 + (nf * 4 + c) * 64 + lane];
                }
                if (ok) {
                    if (s == 1 && c == wid) { xch[nf] = bh.v; xcl[nf] = bl.v; }
                    #pragma unroll
                    for (int mf = 0; mf < 4; mf++) {
                        acc[mf][nf] = __builtin_amdgcn_mfma_f32_16x16x32_bf16(Ah[mf], bh.s8, acc[mf][nf], 0, 0, 0);
                        acc[mf][nf] = __builtin_amdgcn_mfma_f32_16x16x32_bf16(Al[mf], bh.s8, acc[mf][nf], 0, 0, 0);
                        acc[mf][nf] = __builtin_amdgcn_mfma_f32_16x16x32_bf16(Ah[mf], bl.s8, acc[mf][nf], 0, 0, 0);
                    }
                }
            }
        }
    }
    if (!direct) __syncthreads();   // all S reads done before gated-frag overwrite

    // ---- gating -> S in frag layout (c = wid, j = r + 4*mf2) ----
    const int cb = 4 * (lane >> 4);
    float bt[2][4], bsg[2][4];
    #pragma unroll
    for (int mf2 = 0; mf2 < 2; mf2++)
        #pragma unroll
        for (int r = 0; r < 4; r++) {
            int ch = (2 * wid + mf2) * 16 + cb + r;
            bt[mf2][r] = gb[ch];
            bsg[mf2][r] = gb[128 + ch];
        }
    #pragma unroll
    for (int nf = 0; nf < 4; nf++) {
        U4S8 h4, l4;
        #pragma unroll
        for (int mf2 = 0; mf2 < 2; mf2++)
            #pragma unroll
            for (int r = 0; r < 4; r++) {
                float g1 = acc[mf2][nf][r] + bt[mf2][r];
                float g2 = acc[mf2 + 2][nf][r] + bsg[mf2][r];
                float gv = fast_gate(g1, g2);
                unsigned short hi, lo; bsplit(gv, hi, lo);
                h4.us[mf2 * 4 + r] = hi;
                l4.us[mf2 * 4 + r] = lo;
            }
        S[(nf * 4 + wid) * 64 + lane] = h4.v;
        S[1024 + (nf * 4 + wid) * 64 + lane] = l4.v;
    }
    __syncthreads();

    // ---- skip 1x1 GEMM ----
    f32x4 acc2[2][4];
    #pragma unroll
    for (int mf2 = 0; mf2 < 2; mf2++)
        #pragma unroll
        for (int nf = 0; nf < 4; nf++) acc2[mf2][nf] = z4;
    const short8* sp = (const short8*)Spk;
    #pragma unroll
    for (int c = 0; c < 4; c++) {
        short8 A2h[2], A2l[2];
        #pragma unroll
        for (int mf2 = 0; mf2 < 2; mf2++) {
            int ib = (c * 8 + 2 * wid + mf2) * 128 + lane;
            A2h[mf2] = sp[ib];
            A2l[mf2] = sp[ib + 64];
        }
        #pragma unroll
        for (int nf = 0; nf < 4; nf++) {
            U4S8 bh, bl;
            bh.v = S[(nf * 4 + c) * 64 + lane];
            bl.v = S[1024 + (nf * 4 + c) * 64 + lane];
            #pragma unroll
            for (int mf2 = 0; mf2 < 2; mf2++) {
                acc2[mf2][nf] = __builtin_amdgcn_mfma_f32_16x16x32_bf16(A2h[mf2], bh.s8, acc2[mf2][nf], 0, 0, 0);
                acc2[mf2][nf] = __builtin_amdgcn_mfma_f32_16x16x32_bf16(A2l[mf2], bh.s8, acc2[mf2][nf], 0, 0, 0);
                acc2[mf2][nf] = __builtin_amdgcn_mfma_f32_16x16x32_bf16(A2h[mf2], bl.s8, acc2[mf2][nf], 0, 0, 0);
            }
        }
    }

    // ---- epilogue: y = s + x_center (regs), write frag-order coalesced ----
    float bo2[2][4];
    #pragma unroll
    for (int mf2 = 0; mf2 < 2; mf2++)
        #pragma unroll
        for (int r = 0; r < 4; r++) bo2[mf2][r] = skb[(2 * wid + mf2) * 16 + cb + r];
    #pragma unroll
    for (int nf = 0; nf < 4; nf++) {
        U4S8 xh, xl, oh, ol;
        xh.v = xch[nf]; xl.v = xcl[nf];
        #pragma unroll
        for (int j = 0; j < 8; j++) {
            int mf2 = j >> 2, r = j & 3;
            float xin = b2f(xh.us[j]) + b2f(xl.us[j]);
            float sv = acc2[mf2][nf][r] + bo2[mf2][r];
            unsigned short hi, lo; bsplit(sv + xin, hi, lo);
            oh.us[j] = hi; ol.us[j] = lo;
        }
        size_t gi = fidx(n, tb0 + nf, wid, lane);
        Yh[gi] = oh.v; Yl[gi] = ol.v;
    }
}

// ======================= fused output stack (frag-tile) =======================
__global__ __launch_bounds__(256, 2)
void os_fused(const uint4* __restrict__ Fh, const uint4* __restrict__ Fl,
              const uint4* __restrict__ Ih, const uint4* __restrict__ Il,
              const unsigned short* __restrict__ Opk1, const float* __restrict__ o1b,
              const unsigned short* __restrict__ Opk2, const float* __restrict__ o2b,
              const float* __restrict__ o3w, const float* __restrict__ o3b,
              float* __restrict__ out)
{
    __shared__ __align__(16) uint4 SA[2048];   // 32KB frag; later reused as f32 [64][128] xor tile
    __shared__ __align__(16) uint4 SB[2048];   // 32KB frag
    const int n = blockIdx.y, tb0 = blockIdx.x * 4, t0 = tb0 * 16;
    const int tid = threadIdx.x, lane = tid & 63, wid = tid >> 6;
    const int tl = lane & 15, cb = 4 * (lane >> 4);
    const f32x4 z4 = {0.f, 0.f, 0.f, 0.f};
    char* ldsA = (char*)SA;

    // P1: relu(xfin - xinit) -> frag pairs in SA
    for (int j = tid; j < 1024; j += 256) {
        int l = j & 63, c = (j >> 6) & 3, nf = j >> 8;
        size_t gi = fidx(n, tb0 + nf, c, l);
        U4S8 fh, fl, ih, il, ho, lo_;
        fh.v = Fh[gi]; fl.v = Fl[gi]; ih.v = Ih[gi]; il.v = Il[gi];
        #pragma unroll
        for (int e = 0; e < 8; e++) {
            float d = (b2f(fh.us[e]) + b2f(fl.us[e])) - (b2f(ih.us[e]) + b2f(il.us[e]));
            d = fmaxf(d, 0.f);
            unsigned short hi, lo; bsplit(d, hi, lo);
            ho.us[e] = hi; lo_.us[e] = lo;
        }
        SA[j] = ho.v; SA[1024 + j] = lo_.v;
    }
    __syncthreads();

    // P2: GEMM1 -> relu -> frag pairs in SB
    {
        f32x4 acc[2][4];
        #pragma unroll
        for (int mf2 = 0; mf2 < 2; mf2++)
            #pragma unroll
            for (int nf = 0; nf < 4; nf++) acc[mf2][nf] = z4;
        const short8* op = (const short8*)Opk1;
        #pragma unroll
        for (int c = 0; c < 4; c++) {
            short8 Ah[2], Al[2];
            #pragma unroll
            for (int mf2 = 0; mf2 < 2; mf2++) {
                int ib = (c * 8 + 2 * wid + mf2) * 128 + lane;
                Ah[mf2] = op[ib]; Al[mf2] = op[ib + 64];
            }
            #pragma unroll
            for (int nf = 0; nf < 4; nf++) {
                U4S8 bh, bl;
                bh.v = SA[(nf * 4 + c) * 64 + lane];
                bl.v = SA[1024 + (nf * 4 + c) * 64 + lane];
                #pragma unroll
                for (int mf2 = 0; mf2 < 2; mf2++) {
                    acc[mf2][nf] = __builtin_amdgcn_mfma_f32_16x16x32_bf16(Ah[mf2], bh.s8, acc[mf2][nf], 0, 0, 0);
                    acc[mf2][nf] = __builtin_amdgcn_mfma_f32_16x16x32_bf16(Al[mf2], bh.s8, acc[mf2][nf], 0, 0, 0);
                    acc[mf2][nf] = __builtin_amdgcn_mfma_f32_16x16x32_bf16(Ah[mf2], bl.s8, acc[mf2][nf], 0, 0, 0);
                }
            }
        }
        #pragma unroll
        for (int nf = 0; nf < 4; nf++) {
            U4S8 h4, l4;
            #pragma unroll
            for (int mf2 = 0; mf2 < 2; mf2++)
                #pragma unroll
                for (int r = 0; r < 4; r++) {
                    float v = fmaxf(acc[mf2][nf][r] + o1b[(2 * wid + mf2) * 16 + cb + r], 0.f);
                    unsigned short hi, lo; bsplit(v, hi, lo);
                    h4.us[mf2 * 4 + r] = hi; l4.us[mf2 * 4 + r] = lo;
                }
            SB[(nf * 4 + wid) * 64 + lane] = h4.v;
            SB[1024 + (nf * 4 + wid) * 64 + lane] = l4.v;
        }
    }
    __syncthreads();

    // P3: GEMM2 -> relu -> f32 xor tile in SA
    {
        f32x4 acc[2][4];
        #pragma unroll
        for (int mf2 = 0; mf2 < 2; mf2++)
            #pragma unroll
            for (int nf = 0; nf < 4; nf++) acc[mf2][nf] = z4;
        const short8* op = (const short8*)Opk2;
        #pragma unroll
        for (int c = 0; c < 4; c++) {
            short8 Ah[2], Al[2];
            #pragma unroll
            for (int mf2 = 0; mf2 < 2; mf2++) {
                int ib = (c * 8 + 2 * wid + mf2) * 128 + lane;
                Ah[mf2] = op[ib]; Al[mf2] = op[ib + 64];
            }
            #pragma unroll
            for (int nf = 0; nf < 4; nf++) {
                U4S8 bh, bl;
                bh.v = SB[(nf * 4 + c) * 64 + lane];
                bl.v = SB[1024 + (nf * 4 + c) * 64 + lane];
                #pragma unroll
                for (int mf2 = 0; mf2 < 2; mf2++) {
                    acc[mf2][nf] = __builtin_amdgcn_mfma_f32_16x16x32_bf16(Ah[mf2], bh.s8, acc[mf2][nf], 0, 0, 0);
                    acc[mf2][nf] = __builtin_amdgcn_mfma_f32_16x16x32_bf16(Al[mf2], bh.s8, acc[mf2][nf], 0, 0, 0);
                    acc[mf2][nf] = __builtin_amdgcn_mfma_f32_16x16x32_bf16(Ah[mf2], bl.s8, acc[mf2][nf], 0, 0, 0);
                }
            }
        }
        __syncthreads();   // SA (frag) reads all done -> reuse as f32 tile
        #pragma unroll
        for (int mf2 = 0; mf2 < 2; mf2++) {
            const int ch0 = (2 * wid + mf2) * 16 + cb;
            #pragma unroll
            for (int nf = 0; nf < 4; nf++) {
                int row = nf * 16 + tl, swz = (row & 7) << 4;
                float4 v;
                v.x = fmaxf(acc[mf2][nf][0] + o2b[ch0 + 0], 0.f);
                v.y = fmaxf(acc[mf2][nf][1] + o2b[ch0 + 1], 0.f);
                v.z = fmaxf(acc[mf2][nf][2] + o2b[ch0 + 2], 0.f);
                v.w = fmaxf(acc[mf2][nf][3] + o2b[ch0 + 3], 0.f);
                *(float4*)(ldsA + row * 512 + ((ch0 * 4) ^ swz)) = v;
            }
        }
    }
    __syncthreads();

    // P4: final 1-ch conv + tanh
    {
        const int t_loc = tid >> 2, qq = tid & 3;
        const int row = t_loc, swz = (row & 7) << 4;
        float a = 0.f;
        #pragma unroll
        for (int cc = 0; cc < 8; cc++) {
            int ch = qq * 32 + cc * 4;
            float4 v = *(const float4*)(ldsA + row * 512 + ((ch * 4) ^ swz));
            a += o3w[ch] * v.x + o3w[ch + 1] * v.y + o3w[ch + 2] * v.z + o3w[ch + 3] * v.w;
        }
        a += __shfl_xor(a, 1);
        a += __shfl_xor(a, 2);
        if (qq == 0) out[(size_t)n * T_LEN + t0 + t_loc] = tanhf(a + o3b[0]);
    }
}

// ======================= launch =======================
extern "C" void kernel_launch(void* const* d_in, const int* in_sizes, int n_in,
                              void* d_out, int out_size, void* d_ws, size_t ws_size,
                              hipStream_t stream)
{
    (void)in_sizes; (void)n_in; (void)out_size; (void)ws_size;
    const float* mel    = (const float*)d_in[0];
    const float* in_w   = (const float*)d_in[1];
    const float* in_b   = (const float*)d_in[2];
    const float* pre_w  = (const float*)d_in[3];
    const float* pre_b  = (const float*)d_in[4];
    const float* up1_w  = (const float*)d_in[5];
    const float* up1_b  = (const float*)d_in[6];
    const float* up2_w  = (const float*)d_in[7];
    const float* up2_b  = (const float*)d_in[8];
    const float* wn_wsp = (const float*)d_in[9];
    const float* wn_bs  = (const float*)d_in[10];
    const float* sk_wsp = (const float*)d_in[11];
    const float* sk_bs  = (const float*)d_in[12];
    const float* o1w = (const float*)d_in[13];
    const float* o1b = (const float*)d_in[14];
    const float* o2w = (const float*)d_in[15];
    const float* o2b = (const float*)d_in[16];
    const float* o3w = (const float*)d_in[17];
    const float* o3b = (const float*)d_in[18];

    // each bf16 plane: 8,388,608 elems = 16,777,216 BYTES
    char* base = (char*)d_ws;
    uint4* XAh = (uint4*)(base);
    uint4* XAl = (uint4*)(base + 16777216);
    uint4* XBh = (uint4*)(base + 33554432);
    uint4* XBl = (uint4*)(base + 50331648);
    uint4* XCh = (uint4*)(base + 67108864);
    uint4* XCl = (uint4*)(base + 83886080);
    unsigned short* Apk = (unsigned short*)(base + 100663296);   // 11,796,480 B
    unsigned short* Spk = (unsigned short*)(base + 112459776);   //  1,966,080 B
    unsigned short* Opk1 = (unsigned short*)(base + 114425856);  //     65,536 B
    unsigned short* Opk2 = (unsigned short*)(base + 114491392);  //     65,536 B
    float* a64   = (float*)(base + 114556928);
    float* b64   = (float*)(base + 114688000);
    float* x256  = (float*)(base + 114819072);
    float* x1024 = (float*)(base + 115343360);

    prep_w3<<<488, 256, 0, stream>>>(wn_wsp, sk_wsp, o1w, o2w, Apk, Spk, Opk1, Opk2);

    fe_in<<<dim3(64, 4), 128, 0, stream>>>(mel, in_w, in_b, a64);
    fe_pre<<<dim3(64, 4), 128, 0, stream>>>(a64, b64, pre_w + 0 * 49152, pre_b + 0 * 128, 1);
    fe_pre<<<dim3(64, 4), 128, 0, stream>>>(b64, a64, pre_w + 1 * 49152, pre_b + 1 * 128, 2);
    fe_pre<<<dim3(64, 4), 128, 0, stream>>>(a64, b64, pre_w + 2 * 49152, pre_b + 2 * 128, 4);
    fe_pre<<<dim3(64, 4), 128, 0, stream>>>(b64, a64, pre_w + 3 * 49152, pre_b + 3 * 128, 8);
    fe_pre<<<dim3(64, 4), 128, 0, stream>>>(a64, b64, pre_w + 4 * 49152, pre_b + 4 * 128, 16);
    fe_up3<<<dim3(4, 4), 256, 0, stream>>>(b64, x256, up1_w, up1_b, 64);
    fe_up3<<<dim3(16, 4), 256, 0, stream>>>(x256, x1024, up2_w, up2_b, 256);
    fe_repeat_f<<<dim3(16, 4), 256, 0, stream>>>(x1024, XAh, XAl);

    for (int li = 0; li < 30; li++) {
        int d = 1 << (li % 10);
        const uint4 *ih, *il; uint4 *oh, *ol;
        if (li == 0)      { ih = XAh; il = XAl; oh = XBh; ol = XBl; }
        else if (li & 1)  { ih = XBh; il = XBl; oh = XCh; ol = XCl; }
        else              { ih = XCh; il = XCl; oh = XBh; ol = XBl; }
        wn_layer<<<dim3(T_LEN / 64, 4), 256, 0, stream>>>(
            ih, il, oh, ol,
            Apk + (size_t)li * 196608, wn_bs + li * 256,
            Spk + (size_t)li * 32768, sk_bs + li * 128, d);
    }

    // skips = x_final - x_init
    os_fused<<<dim3(T_LEN / 64, 4), 256, 0, stream>>>(
        XCh, XCl, XAh, XAl, Opk1, o1b, Opk2, o2b, o3w, o3b, (float*)d_out);
}